// Round 3
// baseline (927.230 us; speedup 1.0000x reference)
//
#include <hip/hip_runtime.h>

#define S_ROWS 16384
#define T_ROWS 32768
#define NROWS  49152
#define DDIM   4096
#define C      21
#define KSPLIT 4

// workspace layout (in floats)
#define WT_OFF 0
#define WT_SZ  (C * DDIM)              // 86016: W transposed to [C][D]
#define P_OFF  (WT_OFF + WT_SZ)
#define P_SLOT (NROWS * C)             // 1032192 per k-slot
#define DM_OFF (P_OFF + KSPLIT * P_SLOT)
#define N_OFF  (DM_OFF + C)
#define NW_OFF (N_OFF + C)

// ---------------- kernel 1: transpose W, zero accumulators ----------------
__global__ void k_prep(const float* __restrict__ W, float* __restrict__ ws) {
    int idx = blockIdx.x * 256 + threadIdx.x;
    if (idx < C * DDIM) {
        int c = idx / DDIM, d = idx - c * DDIM;
        ws[WT_OFF + idx] = W[d * C + c];
    }
    if (blockIdx.x == 0 && threadIdx.x < 2 * C) {
        ws[DM_OFF + threadIdx.x] = 0.0f;   // zeroes delta_margin[21] + num[21]
    }
}

// ---------------- kernel 2: tiled GEMM partials -------------------------
// block: 256 threads = 4 waves; 256 rows/block; grid (192 row-groups, 4 k-chunks)
// wave w covers d-subrange [w*8, w*8+8) of each 32-wide k-tile; lane l owns rows
// l, l+64, l+128, l+192. acc[4][21] in registers; W tile broadcast from LDS.
//
// REGISTER-PRESSURE DISCIPLINE (R0/R1 spilled acc at launch_bounds(256,3);
// fix was (256,2) -> spill-free, 468us):
//  - acc indices always compile-time constants; 4-wide dd passes (unroll 1).
//
// LATENCY PIPELINE (R3): R2 counters showed latency-bound serialization
// (HBM 12.7%, VALU 20%, occupancy 18%): load->ds_write->barrier->compute
// exposed full HBM latency every t-iter. Fix = issue-early/write-late
// register double-buffer: loads for tile t+1 are issued BEFORE computing
// tile t; the ds_write at the top of iter t+1 is where the compiler waits
// on them. HBM latency hides under the compute phase.
__launch_bounds__(256, 2)
__global__ void k_gemm(const float* __restrict__ src, const float* __restrict__ tgt,
                       float* __restrict__ ws) {
    __shared__ float smem[10752];           // 43008 B: stage (9888 fl) / red (10752 fl)
    const int tid = threadIdx.x;
    const int g   = blockIdx.x;             // row group (256 rows)
    const int ks  = blockIdx.y;             // k chunk (1024 d)
    const int l   = tid & 63, w = tid >> 6;
    const int w8  = w * 8;
    const int rg0 = g * 256;
    const float* xb = (rg0 < S_ROWS) ? (src + (size_t)rg0 * DDIM)
                                     : (tgt + (size_t)(rg0 - S_ROWS) * DDIM);
    const float* wt = ws + WT_OFF;

    // hoisted staging addresses: global pointers + LDS offsets (fixed per thread)
    const float* xp[8];
    int soff[8];
#pragma unroll
    for (int it = 0; it < 8; ++it) {
        int f = it * 256 + tid;
        int row = f >> 3, j4 = (f & 7) << 2;
        xp[it]   = xb + (size_t)row * DDIM + ks * 1024 + j4;
        soff[it] = row * 36 + j4;
    }
    const bool wact = (tid < 168);
    const float* wp = wt;
    int wsoff = 0;
    if (wact) {
        int c = tid >> 3, j4 = (tid & 7) << 2;
        wp    = wt + (size_t)c * DDIM + ks * 1024 + j4;
        wsoff = 9216 + c * 32 + j4;
    }

    float acc[4][C];
#pragma unroll
    for (int r = 0; r < 4; ++r)
#pragma unroll
        for (int c = 0; c < C; ++c) acc[r][c] = 0.0f;

    // prologue: load tile 0 into registers
    float4 xstage[8], wstage;
#pragma unroll
    for (int it = 0; it < 8; ++it) xstage[it] = *(const float4*)xp[it];
    if (wact) wstage = *(const float4*)wp;

#pragma unroll 1
    for (int t = 0; t < 32; ++t) {
        // write staged tile (regs -> LDS); compiler inserts the vmcnt wait here
#pragma unroll
        for (int it = 0; it < 8; ++it)
            *(float4*)&smem[soff[it]] = xstage[it];
        if (wact) *(float4*)&smem[wsoff] = wstage;
        __syncthreads();

        // issue NEXT tile's loads now; they drain during the compute below
        if (t < 31) {
#pragma unroll
            for (int it = 0; it < 8; ++it) {
                xstage[it] = *(const float4*)(xp[it] + 32);
                xp[it] += 32;
            }
            if (wact) { wstage = *(const float4*)(wp + 32); wp += 32; }
        }

        // two sequential 4-wide passes over this wave's 8-wide d-slice
#pragma unroll 1
        for (int dd = 0; dd < 8; dd += 4) {
            float4 xr[4];
#pragma unroll
            for (int r = 0; r < 4; ++r)
                xr[r] = *(const float4*)&smem[(l + r * 64) * 36 + w8 + dd];
#pragma unroll
            for (int c = 0; c < C; ++c) {
                float4 wv = *(const float4*)&smem[9216 + c * 32 + w8 + dd];
#pragma unroll
                for (int r = 0; r < 4; ++r) {
                    acc[r][c] += xr[r].x * wv.x + xr[r].y * wv.y +
                                 xr[r].z * wv.z + xr[r].w * wv.w;
                }
            }
        }
        __syncthreads();
    }

    // cross-wave reduction (two halves of 128 rows to fit LDS), store partials
    float* pout = ws + P_OFF + (size_t)ks * P_SLOT;
#pragma unroll
    for (int h = 0; h < 2; ++h) {
#pragma unroll
        for (int c = 0; c < C; ++c) {
            smem[w * 2688 + l * 21 + c]        = acc[2 * h][c];
            smem[w * 2688 + (l + 64) * 21 + c] = acc[2 * h + 1][c];
        }
        __syncthreads();
        for (int idx = tid; idx < 2688; idx += 256) {
            int row = idx / 21, c = idx - row * 21;
            float s = smem[row * 21 + c] + smem[2688 + row * 21 + c] +
                      smem[5376 + row * 21 + c] + smem[8064 + row * 21 + c];
            pout[(size_t)(rg0 + h * 128 + row) * 21 + c] = s;
        }
        __syncthreads();
    }
}

// ---------------- kernel 3: sum partials, softmax, stats ----------------
__global__ void k_phaseB(const float* __restrict__ b_cls, float* __restrict__ ws,
                         float* __restrict__ out) {
    const int tid = threadIdx.x;
    const int row = blockIdx.x * 256 + tid;
    const float* P = ws + P_OFF;
    float lg[C];
#pragma unroll
    for (int c = 0; c < C; ++c) lg[c] = b_cls[c];
    for (int k = 0; k < KSPLIT; ++k) {
        const float* p = P + (size_t)k * P_SLOT + (size_t)row * C;
#pragma unroll
        for (int c = 0; c < C; ++c) lg[c] += p[c];
    }
    float m = lg[0];
#pragma unroll
    for (int c = 1; c < C; ++c) m = fmaxf(m, lg[c]);
    float e[C], s = 0.0f;
#pragma unroll
    for (int c = 0; c < C; ++c) { e[c] = __expf(lg[c] - m); s += e[c]; }
    float inv = 1.0f / s;

    if (row < S_ROWS) {                    // block-uniform branch (64 src blocks)
        float* o = out + (size_t)row * 22;
#pragma unroll
        for (int c = 0; c < C; ++c) o[c] = e[c] * inv;
    } else {
        __shared__ float s_dm[C], s_n[C];
        if (tid < C) { s_dm[tid] = 0.0f; s_n[tid] = 0.0f; }
        __syncthreads();
        float top = -1.0f, sum = 0.0f; int arg = 0;
#pragma unroll
        for (int c = 0; c < C; ++c) {
            float p = e[c] * inv; sum += p;
            if (p > top) { top = p; arg = c; }   // strict > keeps first argmax
        }
        float margin = top - (sum - top) * (1.0f / (C - 1));
        if (arg != 0) {
            atomicAdd(&s_dm[arg], margin);
            atomicAdd(&s_n[arg], 1.0f);
        }
        __syncthreads();
        if (tid < C) {
            atomicAdd(&ws[DM_OFF + tid], s_dm[tid]);
            atomicAdd(&ws[N_OFF + tid], s_n[tid]);
        }
    }
}

// ---------------- kernel 4: blend + minmax normalize (1 block) ----------
__global__ void k_final(const float* __restrict__ tmf, const float* __restrict__ rec,
                        float* __restrict__ ws) {
    __shared__ float wv[C];
    __shared__ float mm[2];
    const int t = threadIdx.x;
    if (t < C) {
        float r = rec[0];
        float n = ws[N_OFF + t];
        float blended = (tmf[t] * r + ws[DM_OFF + t] / (n + 1e-6f)) / (r + 1.0f);
        float sn = 0.0f;
        for (int c = 0; c < C; ++c) sn += ws[N_OFF + c];
        wv[t] = (sn > 0.0f) ? blended : tmf[t];
    }
    __syncthreads();
    if (t == 0) {
        float mn = wv[0], mx = wv[0];
        for (int c = 1; c < C; ++c) { mn = fminf(mn, wv[c]); mx = fmaxf(mx, wv[c]); }
        mm[0] = mn; mm[1] = mx;
    }
    __syncthreads();
    if (t < C) ws[NW_OFF + t] = (wv[t] - mm[0]) / (mm[1] - mm[0] + 1e-12f);
}

// ---------------- kernel 5: gather weight column ------------------------
__global__ void k_gather(const int* __restrict__ label, const float* __restrict__ ws,
                         float* __restrict__ out) {
    int s = blockIdx.x * 256 + threadIdx.x;
    out[(size_t)s * 22 + 21] = ws[NW_OFF + label[s]];
}

extern "C" void kernel_launch(void* const* d_in, const int* in_sizes, int n_in,
                              void* d_out, int out_size, void* d_ws, size_t ws_size,
                              hipStream_t stream) {
    const float* src   = (const float*)d_in[0];
    const float* tgt   = (const float*)d_in[1];
    const float* W     = (const float*)d_in[2];
    const float* b     = (const float*)d_in[3];
    const int*   label = (const int*)d_in[4];
    const float* tmf   = (const float*)d_in[5];
    const float* rec   = (const float*)d_in[6];
    float* out = (float*)d_out;
    float* ws  = (float*)d_ws;

    k_prep<<<(C * DDIM + 255) / 256, 256, 0, stream>>>(W, ws);
    k_gemm<<<dim3(192, KSPLIT), 256, 0, stream>>>(src, tgt, ws);
    k_phaseB<<<NROWS / 256, 256, 0, stream>>>(b, ws, out);
    k_final<<<1, 64, 0, stream>>>(tmf, rec, ws);
    k_gather<<<S_ROWS / 256, 256, 0, stream>>>(label, ws, out);
}

// Round 4
// 330.025 us; speedup vs baseline: 2.8096x; 2.8096x over previous
//
#include <hip/hip_runtime.h>

#define S_ROWS 16384
#define T_ROWS 32768
#define NROWS  49152
#define DDIM   4096
#define C      21
#define KSPLIT 4

// workspace layout (in floats)
#define WT_OFF 0
#define WT_SZ  (C * DDIM)              // 86016: W transposed to [C][D]
#define P_OFF  (WT_OFF + WT_SZ)
#define P_SLOT (NROWS * C)             // 1032192 per k-slot
#define DM_OFF (P_OFF + KSPLIT * P_SLOT)
#define N_OFF  (DM_OFF + C)
#define NW_OFF (N_OFF + C)

// LDS layout for k_gemm (floats): double-buffered X + W tiles
#define XB0 0
#define XB1 8192
#define WB0 16384
#define WB1 (16384 + 768)
#define SMEM_FL 17920                  // 71680 B; reduction reuses [0..10752)

// ---------------- kernel 1: transpose W, zero accumulators ----------------
__global__ void k_prep(const float* __restrict__ W, float* __restrict__ ws) {
    int idx = blockIdx.x * 256 + threadIdx.x;
    if (idx < C * DDIM) {
        int c = idx / DDIM, d = idx - c * DDIM;
        ws[WT_OFF + idx] = W[d * C + c];
    }
    if (blockIdx.x == 0 && threadIdx.x < 2 * C) {
        ws[DM_OFF + threadIdx.x] = 0.0f;   // zeroes delta_margin[21] + num[21]
    }
}

// async 16B global->LDS DMA (zero VGPR round-trip; lds dest = wave base + lane*16)
typedef const __attribute__((address_space(1))) void* gas_ptr;
typedef __attribute__((address_space(3))) void* las_ptr;
__device__ __forceinline__ void gload_lds16(const float* g, float* l) {
    __builtin_amdgcn_global_load_lds((gas_ptr)g, (las_ptr)l, 16, 0, 0);
}

// ---------------- kernel 2: tiled GEMM partials -------------------------
// block: 256 threads = 4 waves; 256 rows/block; grid (192 row-groups, 4 k-chunks)
// wave w covers d-subrange [w*8, w*8+8) of each 32-wide k-tile; lane l owns rows
// l, l+64, l+128, l+192. acc[4][21] in registers; W tile broadcast from LDS.
//
// HISTORY / DISCIPLINE:
//  - R0/R1: acc spilled under launch_bounds(256,3); fix = (256,2). 468us.
//  - R3: reg-staged prefetch (xstage[9] float4 live across compute) re-spilled
//    (WRITE_SIZE 1GB, conflicts 1.5M) -> 927us. Lesson: prefetch must cost 0 VGPR.
//  - R4 (this): T3 2-phase template with __builtin_amdgcn_global_load_lds into
//    double-buffered LDS. One barrier/iter; DMA for tile t+1 flies under the
//    compute of tile t; vmcnt drains at the end-of-iter barrier.
//  - gload_lds writes linearly (wave base + lane*16) so the stride-36 pad is
//    impossible; instead XOR-swizzle (rule 21, both-sides): physical float4
//    slot = row*8 + (f ^ (row&7)). DMA pre-swizzles the per-lane GLOBAL
//    address (same 128B segment per 8-lane group -> coalescing intact); the
//    ds_read applies the same XOR -> each 8-lane group covers all 32 banks
//    exactly once -> conflict-free. W tile is broadcast-read -> plain linear.
__launch_bounds__(256, 2)
__global__ void k_gemm(const float* __restrict__ src, const float* __restrict__ tgt,
                       float* __restrict__ ws) {
    __shared__ float smem[SMEM_FL];
    const int tid = threadIdx.x;
    const int g   = blockIdx.x;             // row group (256 rows)
    const int ks  = blockIdx.y;             // k chunk (1024 d)
    const int l   = tid & 63, w = tid >> 6;
    const int w8  = w * 8;
    const int rg0 = g * 256;
    const float* xb = (rg0 < S_ROWS) ? (src + (size_t)rg0 * DDIM)
                                     : (tgt + (size_t)(rg0 - S_ROWS) * DDIM);
    const float* wt = ws + WT_OFF;

    // per-lane pre-swizzled global source pointers for the 8 X DMA calls
    const int r8 = l >> 3, c8 = l & 7;
    const int fsw_src = (c8 ^ r8) << 2;     // swizzled float4 -> float offset
    const float* xg[8];
#pragma unroll
    for (int i = 0; i < 8; ++i)
        xg[i] = xb + (size_t)((w * 8 + i) * 8 + r8) * DDIM + ks * 1024 + fsw_src;
    // W DMA: waves 0..2 each cover 8 rows (rows 21..23 read harmless ws garbage)
    const float* wg = wt + (size_t)(w * 8 + r8) * DDIM + ks * 1024 + (c8 << 2);

    float acc[4][C];
#pragma unroll
    for (int r = 0; r < 4; ++r)
#pragma unroll
        for (int c = 0; c < C; ++c) acc[r][c] = 0.0f;

    // prologue: stage tile 0 into buffer 0
#pragma unroll
    for (int i = 0; i < 8; ++i)
        gload_lds16(xg[i], &smem[XB0 + (w * 8 + i) * 256]);
    if (w < 3) gload_lds16(wg, &smem[WB0 + w * 256]);
    __syncthreads();

#pragma unroll 1
    for (int t = 0; t < 32; ++t) {
        const int xcur = (t & 1) ? XB1 : XB0;
        const int wcur = (t & 1) ? WB1 : WB0;
        // issue DMA for tile t+1 into the other buffer (flies under compute)
        if (t < 31) {
            const int xnxt = (t & 1) ? XB0 : XB1;
            const int wnxt = (t & 1) ? WB0 : WB1;
            const int koff = (t + 1) * 32;
#pragma unroll
            for (int i = 0; i < 8; ++i)
                gload_lds16(xg[i] + koff, &smem[xnxt + (w * 8 + i) * 256]);
            if (w < 3) gload_lds16(wg + koff, &smem[wnxt + w * 256]);
        }

        // two sequential 4-wide passes over this wave's 8-wide d-slice
#pragma unroll 1
        for (int dd = 0; dd < 8; dd += 4) {
            const int f4 = w * 2 + (dd >> 2);   // logical float4 slot
            float4 xr[4];
#pragma unroll
            for (int r = 0; r < 4; ++r) {
                const int row = l + r * 64;
                xr[r] = *(const float4*)
                    &smem[xcur + row * 32 + ((f4 ^ (row & 7)) << 2)];
            }
#pragma unroll
            for (int c = 0; c < C; ++c) {
                float4 wv = *(const float4*)&smem[wcur + c * 32 + w8 + dd];
#pragma unroll
                for (int r = 0; r < 4; ++r) {
                    acc[r][c] += xr[r].x * wv.x + xr[r].y * wv.y +
                                 xr[r].z * wv.z + xr[r].w * wv.w;
                }
            }
        }
        __syncthreads();   // drains DMA vmcnt + lgkm; one barrier per iter
    }

    // cross-wave reduction (two halves of 128 rows to fit LDS), store partials
    float* pout = ws + P_OFF + (size_t)ks * P_SLOT;
#pragma unroll
    for (int h = 0; h < 2; ++h) {
#pragma unroll
        for (int c = 0; c < C; ++c) {
            smem[w * 2688 + l * 21 + c]        = acc[2 * h][c];
            smem[w * 2688 + (l + 64) * 21 + c] = acc[2 * h + 1][c];
        }
        __syncthreads();
        for (int idx = tid; idx < 2688; idx += 256) {
            int row = idx / 21, c = idx - row * 21;
            float s = smem[row * 21 + c] + smem[2688 + row * 21 + c] +
                      smem[5376 + row * 21 + c] + smem[8064 + row * 21 + c];
            pout[(size_t)(rg0 + h * 128 + row) * 21 + c] = s;
        }
        __syncthreads();
    }
}

// ---------------- kernel 3: sum partials, softmax, stats ----------------
__global__ void k_phaseB(const float* __restrict__ b_cls, float* __restrict__ ws,
                         float* __restrict__ out) {
    const int tid = threadIdx.x;
    const int row = blockIdx.x * 256 + tid;
    const float* P = ws + P_OFF;
    float lg[C];
#pragma unroll
    for (int c = 0; c < C; ++c) lg[c] = b_cls[c];
    for (int k = 0; k < KSPLIT; ++k) {
        const float* p = P + (size_t)k * P_SLOT + (size_t)row * C;
#pragma unroll
        for (int c = 0; c < C; ++c) lg[c] += p[c];
    }
    float m = lg[0];
#pragma unroll
    for (int c = 1; c < C; ++c) m = fmaxf(m, lg[c]);
    float e[C], s = 0.0f;
#pragma unroll
    for (int c = 0; c < C; ++c) { e[c] = __expf(lg[c] - m); s += e[c]; }
    float inv = 1.0f / s;

    if (row < S_ROWS) {                    // block-uniform branch (64 src blocks)
        float* o = out + (size_t)row * 22;
#pragma unroll
        for (int c = 0; c < C; ++c) o[c] = e[c] * inv;
    } else {
        __shared__ float s_dm[C], s_n[C];
        if (tid < C) { s_dm[tid] = 0.0f; s_n[tid] = 0.0f; }
        __syncthreads();
        float top = -1.0f, sum = 0.0f; int arg = 0;
#pragma unroll
        for (int c = 0; c < C; ++c) {
            float p = e[c] * inv; sum += p;
            if (p > top) { top = p; arg = c; }   // strict > keeps first argmax
        }
        float margin = top - (sum - top) * (1.0f / (C - 1));
        if (arg != 0) {
            atomicAdd(&s_dm[arg], margin);
            atomicAdd(&s_n[arg], 1.0f);
        }
        __syncthreads();
        if (tid < C) {
            atomicAdd(&ws[DM_OFF + tid], s_dm[tid]);
            atomicAdd(&ws[N_OFF + tid], s_n[tid]);
        }
    }
}

// ---------------- kernel 4: blend + minmax normalize (1 block) ----------
__global__ void k_final(const float* __restrict__ tmf, const float* __restrict__ rec,
                        float* __restrict__ ws) {
    __shared__ float wv[C];
    __shared__ float mm[2];
    const int t = threadIdx.x;
    if (t < C) {
        float r = rec[0];
        float n = ws[N_OFF + t];
        float blended = (tmf[t] * r + ws[DM_OFF + t] / (n + 1e-6f)) / (r + 1.0f);
        float sn = 0.0f;
        for (int c = 0; c < C; ++c) sn += ws[N_OFF + c];
        wv[t] = (sn > 0.0f) ? blended : tmf[t];
    }
    __syncthreads();
    if (t == 0) {
        float mn = wv[0], mx = wv[0];
        for (int c = 1; c < C; ++c) { mn = fminf(mn, wv[c]); mx = fmaxf(mx, wv[c]); }
        mm[0] = mn; mm[1] = mx;
    }
    __syncthreads();
    if (t < C) ws[NW_OFF + t] = (wv[t] - mm[0]) / (mm[1] - mm[0] + 1e-12f);
}

// ---------------- kernel 5: gather weight column ------------------------
__global__ void k_gather(const int* __restrict__ label, const float* __restrict__ ws,
                         float* __restrict__ out) {
    int s = blockIdx.x * 256 + threadIdx.x;
    out[(size_t)s * 22 + 21] = ws[NW_OFF + label[s]];
}

extern "C" void kernel_launch(void* const* d_in, const int* in_sizes, int n_in,
                              void* d_out, int out_size, void* d_ws, size_t ws_size,
                              hipStream_t stream) {
    const float* src   = (const float*)d_in[0];
    const float* tgt   = (const float*)d_in[1];
    const float* W     = (const float*)d_in[2];
    const float* b     = (const float*)d_in[3];
    const int*   label = (const int*)d_in[4];
    const float* tmf   = (const float*)d_in[5];
    const float* rec   = (const float*)d_in[6];
    float* out = (float*)d_out;
    float* ws  = (float*)d_ws;

    k_prep<<<(C * DDIM + 255) / 256, 256, 0, stream>>>(W, ws);
    k_gemm<<<dim3(192, KSPLIT), 256, 0, stream>>>(src, tgt, ws);
    k_phaseB<<<NROWS / 256, 256, 0, stream>>>(b, ws, out);
    k_final<<<1, 64, 0, stream>>>(tmf, rec, ws);
    k_gather<<<S_ROWS / 256, 256, 0, stream>>>(label, ws, out);
}

// Round 5
// 232.248 us; speedup vs baseline: 3.9924x; 1.4210x over previous
//
#include <hip/hip_runtime.h>

#define S_ROWS 16384
#define T_ROWS 32768
#define NROWS  49152
#define DDIM   4096
#define C      21
#define KSPLIT 2

// workspace layout (in floats)
#define WT_OFF 0
#define WT_SZ  (C * DDIM)              // 86016: W transposed to [C][D]
#define P_OFF  (WT_OFF + WT_SZ)
#define P_SLOT (NROWS * C)             // 1032192 per k-slot
#define DM_OFF (P_OFF + KSPLIT * P_SLOT)
#define N_OFF  (DM_OFF + C)
#define NW_OFF (N_OFF + C)

// LDS layout for k_gemm (floats): double-buffered X + W tiles
// X tile: 128 rows x 32 k = 4096 floats; W tile: 24 rows x 32 = 768 floats
#define XB0 0
#define XB1 4096
#define WB0 8192
#define WB1 (8192 + 768)
#define SMEM_FL 9728                   // 38912 B; reduction reuses [0..5376)

// ---------------- kernel 1: transpose W, zero accumulators ----------------
__global__ void k_prep(const float* __restrict__ W, float* __restrict__ ws) {
    int idx = blockIdx.x * 256 + threadIdx.x;
    if (idx < C * DDIM) {
        int c = idx / DDIM, d = idx - c * DDIM;
        ws[WT_OFF + idx] = W[d * C + c];
    }
    if (blockIdx.x == 0 && threadIdx.x < 2 * C) {
        ws[DM_OFF + threadIdx.x] = 0.0f;   // zeroes delta_margin[21] + num[21]
    }
}

// async 16B global->LDS DMA (zero VGPR round-trip; lds dest = wave base + lane*16)
typedef const __attribute__((address_space(1))) void* gas_ptr;
typedef __attribute__((address_space(3))) void* las_ptr;
__device__ __forceinline__ void gload_lds16(const float* g, float* l) {
    __builtin_amdgcn_global_load_lds((gas_ptr)g, (las_ptr)l, 16, 0, 0);
}

// ---------------- kernel 2: tiled GEMM partials -------------------------
// block: 256 threads = 4 waves; 128 rows/block; grid (384 row-groups, 2 k-chunks)
// = 768 blocks = EXACTLY 3 blocks/CU x 256 CU, one round, no tail.
// wave w covers d-subrange [w*8, w*8+8) of each 32-wide k-tile; lane l owns
// rows l, l+64. acc[2][21] in registers; W tile broadcast from LDS.
//
// HISTORY / DISCIPLINE:
//  - R0/R1: acc[4][21] spilled under launch_bounds(256,3); (256,2) fixed. 468us.
//  - R3: reg-staged prefetch re-spilled (WRITE_SIZE 1GB). Prefetch must cost 0 VGPR.
//  - R4: global_load_lds + LDS dbuf, 2 blocks/CU -> 370us, but HBM only 15%:
//    per-iter DMA (33KB, ~6600cyc) >> compute cover (~1344cyc) and only 2
//    barrier-synced blocks/CU -> MLP-starved during each block's vmcnt drain.
//  - R5 (this): halve the block (128 rows, acc[2][21]=42 regs, 38KB LDS) and
//    KSPLIT 4->2 so grid = 768 = exact 3 blocks/CU. Three staggered DMA
//    streams/CU (~54KB in flight) cover HBM latency; spill headroom is wide
//    (cap 168 vs ~100 live).
//  - XOR swizzle unchanged (rule 21 both-sides): physical float4 slot =
//    row*8 + (f ^ (row&7)); DMA pre-swizzles the per-lane GLOBAL address
//    (same 128B segment per 8-lane group -> coalescing intact); ds_read
//    applies the same XOR -> conflict-free. W tile broadcast -> linear.
__launch_bounds__(256, 3)
__global__ void k_gemm(const float* __restrict__ src, const float* __restrict__ tgt,
                       float* __restrict__ ws) {
    __shared__ float smem[SMEM_FL];
    const int tid = threadIdx.x;
    const int g   = blockIdx.x;             // row group (128 rows)
    const int ks  = blockIdx.y;             // k chunk (2048 d)
    const int l   = tid & 63, w = tid >> 6;
    const int w8  = w * 8;
    const int rg0 = g * 128;
    const float* xb = (rg0 < S_ROWS) ? (src + (size_t)rg0 * DDIM)
                                     : (tgt + (size_t)(rg0 - S_ROWS) * DDIM);
    const float* wt = ws + WT_OFF;

    // per-lane pre-swizzled global source pointers for the 4 X DMA calls
    const int r8 = l >> 3, c8 = l & 7;
    const int fsw_src = (c8 ^ r8) << 2;     // swizzled float4 -> float offset
    const float* xg[4];
#pragma unroll
    for (int i = 0; i < 4; ++i)
        xg[i] = xb + (size_t)((w * 4 + i) * 8 + r8) * DDIM + ks * 2048 + fsw_src;
    // W DMA: waves 0..2 each cover 8 rows (rows 21..23 read harmless ws bytes)
    const float* wg = wt + (size_t)(w * 8 + r8) * DDIM + ks * 2048 + (c8 << 2);

    float acc[2][C];
#pragma unroll
    for (int r = 0; r < 2; ++r)
#pragma unroll
        for (int c = 0; c < C; ++c) acc[r][c] = 0.0f;

    // prologue: stage tile 0 into buffer 0
#pragma unroll
    for (int i = 0; i < 4; ++i)
        gload_lds16(xg[i], &smem[XB0 + (w * 4 + i) * 256]);
    if (w < 3) gload_lds16(wg, &smem[WB0 + w * 256]);
    __syncthreads();

#pragma unroll 1
    for (int t = 0; t < 64; ++t) {
        const int xcur = (t & 1) ? XB1 : XB0;
        const int wcur = (t & 1) ? WB1 : WB0;
        // issue DMA for tile t+1 into the other buffer (flies under compute)
        if (t < 63) {
            const int xnxt = (t & 1) ? XB0 : XB1;
            const int wnxt = (t & 1) ? WB0 : WB1;
            const int koff = (t + 1) * 32;
#pragma unroll
            for (int i = 0; i < 4; ++i)
                gload_lds16(xg[i] + koff, &smem[xnxt + (w * 4 + i) * 256]);
            if (w < 3) gload_lds16(wg + koff, &smem[wnxt + w * 256]);
        }

        // two sequential 4-wide passes over this wave's 8-wide d-slice
#pragma unroll 1
        for (int dd = 0; dd < 8; dd += 4) {
            const int f4 = w * 2 + (dd >> 2);   // logical float4 slot
            float4 xr[2];
#pragma unroll
            for (int r = 0; r < 2; ++r) {
                const int row = l + r * 64;
                xr[r] = *(const float4*)
                    &smem[xcur + row * 32 + ((f4 ^ (row & 7)) << 2)];
            }
#pragma unroll
            for (int c = 0; c < C; ++c) {
                float4 wv = *(const float4*)&smem[wcur + c * 32 + w8 + dd];
#pragma unroll
                for (int r = 0; r < 2; ++r) {
                    acc[r][c] += xr[r].x * wv.x + xr[r].y * wv.y +
                                 xr[r].z * wv.z + xr[r].w * wv.w;
                }
            }
        }
        __syncthreads();   // drains DMA vmcnt + lgkm; one barrier per iter
    }

    // cross-wave reduction: two halves of 64 rows (fits 38KB LDS), store partials
    float* pout = ws + P_OFF + (size_t)ks * P_SLOT;
#pragma unroll
    for (int h = 0; h < 2; ++h) {
#pragma unroll
        for (int c = 0; c < C; ++c)
            smem[w * 1344 + l * 21 + c] = acc[h][c];
        __syncthreads();
        for (int idx = tid; idx < 1344; idx += 256) {
            int row = idx / 21, c = idx - row * 21;
            float s = smem[row * 21 + c] + smem[1344 + row * 21 + c] +
                      smem[2688 + row * 21 + c] + smem[4032 + row * 21 + c];
            pout[(size_t)(rg0 + h * 64 + row) * 21 + c] = s;
        }
        __syncthreads();
    }
}

// ---------------- kernel 3: sum partials, softmax, stats ----------------
__global__ void k_phaseB(const float* __restrict__ b_cls, float* __restrict__ ws,
                         float* __restrict__ out) {
    const int tid = threadIdx.x;
    const int row = blockIdx.x * 256 + tid;
    const float* P = ws + P_OFF;
    float lg[C];
#pragma unroll
    for (int c = 0; c < C; ++c) lg[c] = b_cls[c];
    for (int k = 0; k < KSPLIT; ++k) {
        const float* p = P + (size_t)k * P_SLOT + (size_t)row * C;
#pragma unroll
        for (int c = 0; c < C; ++c) lg[c] += p[c];
    }
    float m = lg[0];
#pragma unroll
    for (int c = 1; c < C; ++c) m = fmaxf(m, lg[c]);
    float e[C], s = 0.0f;
#pragma unroll
    for (int c = 0; c < C; ++c) { e[c] = __expf(lg[c] - m); s += e[c]; }
    float inv = 1.0f / s;

    if (row < S_ROWS) {                    // block-uniform branch (64 src blocks)
        float* o = out + (size_t)row * 22;
#pragma unroll
        for (int c = 0; c < C; ++c) o[c] = e[c] * inv;
    } else {
        __shared__ float s_dm[C], s_n[C];
        if (tid < C) { s_dm[tid] = 0.0f; s_n[tid] = 0.0f; }
        __syncthreads();
        float top = -1.0f, sum = 0.0f; int arg = 0;
#pragma unroll
        for (int c = 0; c < C; ++c) {
            float p = e[c] * inv; sum += p;
            if (p > top) { top = p; arg = c; }   // strict > keeps first argmax
        }
        float margin = top - (sum - top) * (1.0f / (C - 1));
        if (arg != 0) {
            atomicAdd(&s_dm[arg], margin);
            atomicAdd(&s_n[arg], 1.0f);
        }
        __syncthreads();
        if (tid < C) {
            atomicAdd(&ws[DM_OFF + tid], s_dm[tid]);
            atomicAdd(&ws[N_OFF + tid], s_n[tid]);
        }
    }
}

// ---------------- kernel 4: blend + minmax normalize (1 block) ----------
__global__ void k_final(const float* __restrict__ tmf, const float* __restrict__ rec,
                        float* __restrict__ ws) {
    __shared__ float wv[C];
    __shared__ float mm[2];
    const int t = threadIdx.x;
    if (t < C) {
        float r = rec[0];
        float n = ws[N_OFF + t];
        float blended = (tmf[t] * r + ws[DM_OFF + t] / (n + 1e-6f)) / (r + 1.0f);
        float sn = 0.0f;
        for (int c = 0; c < C; ++c) sn += ws[N_OFF + c];
        wv[t] = (sn > 0.0f) ? blended : tmf[t];
    }
    __syncthreads();
    if (t == 0) {
        float mn = wv[0], mx = wv[0];
        for (int c = 1; c < C; ++c) { mn = fminf(mn, wv[c]); mx = fmaxf(mx, wv[c]); }
        mm[0] = mn; mm[1] = mx;
    }
    __syncthreads();
    if (t < C) ws[NW_OFF + t] = (wv[t] - mm[0]) / (mm[1] - mm[0] + 1e-12f);
}

// ---------------- kernel 5: gather weight column ------------------------
__global__ void k_gather(const int* __restrict__ label, const float* __restrict__ ws,
                         float* __restrict__ out) {
    int s = blockIdx.x * 256 + threadIdx.x;
    out[(size_t)s * 22 + 21] = ws[NW_OFF + label[s]];
}

extern "C" void kernel_launch(void* const* d_in, const int* in_sizes, int n_in,
                              void* d_out, int out_size, void* d_ws, size_t ws_size,
                              hipStream_t stream) {
    const float* src   = (const float*)d_in[0];
    const float* tgt   = (const float*)d_in[1];
    const float* W     = (const float*)d_in[2];
    const float* b     = (const float*)d_in[3];
    const int*   label = (const int*)d_in[4];
    const float* tmf   = (const float*)d_in[5];
    const float* rec   = (const float*)d_in[6];
    float* out = (float*)d_out;
    float* ws  = (float*)d_ws;

    k_prep<<<(C * DDIM + 255) / 256, 256, 0, stream>>>(W, ws);
    k_gemm<<<dim3(NROWS / 128, KSPLIT), 256, 0, stream>>>(src, tgt, ws);
    k_phaseB<<<NROWS / 256, 256, 0, stream>>>(b, ws, out);
    k_final<<<1, 64, 0, stream>>>(tmf, rec, ws);
    k_gather<<<S_ROWS / 256, 256, 0, stream>>>(label, ws, out);
}